// Round 3
// baseline (2729.911 us; speedup 1.0000x reference)
//
#include <hip/hip_runtime.h>
#include <hip/hip_cooperative_groups.h>

namespace cg = cooperative_groups;

#define NCELLS 512
#define WORD_SZ 64
#define RHEADS 4
#define BATCH 16
#define TSTEPS 32
#define IFSZ 471
#define EPSC 1e-8f
#define NSTRIPE 16

// ---------- helpers ----------
__device__ __forceinline__ float wave_sum(float v) {
#pragma unroll
  for (int m = 32; m >= 1; m >>= 1) v += __shfl_xor(v, m, 64);
  return v;
}
__device__ __forceinline__ float wave_max(float v) {
#pragma unroll
  for (int m = 32; m >= 1; m >>= 1) v = fmaxf(v, __shfl_xor(v, m, 64));
  return v;
}
__device__ __forceinline__ float block_sum(float v, float* s_red, int tid) {
  float w = wave_sum(v);
  if ((tid & 63) == 0) s_red[tid >> 6] = w;
  __syncthreads();
  float tot = 0.f;
#pragma unroll
  for (int i = 0; i < 8; i++) tot += s_red[i];
  __syncthreads();
  return tot;
}
__device__ __forceinline__ float block_max(float v, float* s_red, int tid) {
  float w = wave_max(v);
  if ((tid & 63) == 0) s_red[tid >> 6] = w;
  __syncthreads();
  float tot = s_red[0];
#pragma unroll
  for (int i = 1; i < 8; i++) tot = fmaxf(tot, s_red[i]);
  __syncthreads();
  return tot;
}
__device__ __forceinline__ float softplus_f(float x) {
  return fmaxf(x, 0.f) + log1pf(expf(-fabsf(x)));
}
__device__ __forceinline__ float sigmoid_f(float x) {
  return 1.f / (1.f + expf(-x));
}

// ---------- init: state slot 0 + t=0 ww ingredients (link lives in registers) ----------
__global__ void init_kernel(float* mem, float* rw, float* usage,
                            float* prec, float* wcwb, float* ppb) {
  size_t i = (size_t)blockIdx.x * blockDim.x + threadIdx.x;
  size_t stride = (size_t)gridDim.x * blockDim.x;
  const size_t nmem = (size_t)BATCH * NCELLS * WORD_SZ;
  const size_t nrw = (size_t)BATCH * RHEADS * NCELLS;
  const size_t nu = (size_t)BATCH * NCELLS;
  for (size_t x = i; x < nmem; x += stride) mem[x] = 0.f;
  for (size_t x = i; x < nrw; x += stride) rw[x] = 1.f / NCELLS;
  for (size_t x = i; x < nu; x += stride) {
    usage[x] = 0.f; prec[x] = 0.f;
    wcwb[x] = 1.f / NCELLS;                                   // softmax of zeros
    ppb[0 * nu + x] = ((x & (NCELLS - 1)) == 0) ? 1.f : 0.f;  // alloc = e0
    ppb[1 * nu + x] = 1.f;
    ppb[2 * nu + x] = 1.f;
    ppb[3 * nu + x] = 1.f;
  }
}

// ---------- interface GEMM + activations (once) ----------
__global__ __launch_bounds__(512) void iface_kernel(
    const float* __restrict__ ctrl, const float* __restrict__ W,
    const float* __restrict__ bif, float* __restrict__ iface) {
  int bt = blockIdx.x;
  int tid = threadIdx.x;
  __shared__ float s_ctrl[512];
  __shared__ float s_v[IFSZ];
  s_ctrl[tid] = ctrl[(size_t)bt * 512 + tid];
  __syncthreads();
  if (tid < IFSZ) {
    float acc = bif[tid];
#pragma unroll 8
    for (int k = 0; k < 512; k++) acc = fmaf(s_ctrl[k], W[(size_t)k * IFSZ + tid], acc);
    s_v[tid] = acc;
  }
  __syncthreads();
  if (tid < IFSZ) {
    float v = s_v[tid];
    float o;
    if (tid < 256) o = v;
    else if (tid < 260) o = softplus_f(v);
    else if (tid < 324) o = v;
    else if (tid < 325) o = softplus_f(v);
    else if (tid < 389) o = sigmoid_f(v);
    else if (tid < 453) o = v;
    else if (tid < 459) o = sigmoid_f(v);
    else {
      int g = (tid - 459) / 3;
      int base = 459 + g * 3;
      float a = s_v[base], b = s_v[base + 1], c = s_v[base + 2];
      float mx = fmaxf(a, fmaxf(b, c));
      float ea = expf(a - mx), eb = expf(b - mx), ec = expf(c - mx);
      o = expf(v - mx) / (ea + eb + ec);
    }
    iface[(size_t)bt * IFSZ + tid] = o;
  }
}

// ---------- persistent cooperative kernel: whole T loop; link in registers ----------
__global__ __launch_bounds__(512, 2) void dnc_loop(
    const float* __restrict__ iface,
    float* __restrict__ mem0, float* __restrict__ mem1,
    float* __restrict__ rw0, float* __restrict__ rw1,
    float* __restrict__ us0, float* __restrict__ us1,
    float* __restrict__ pr0, float* __restrict__ pr1,
    float* __restrict__ wcwb, float* __restrict__ ppb,
    float* __restrict__ fwdb, float* __restrict__ bwdp,
    float* __restrict__ out) {
  cg::grid_group grid = cg::this_grid();
  const int blk = blockIdx.x;            // 0..255
  const int stripe = blk >> 4, b = blk & 15;
  const int tid = threadIdx.x, lane = tid & 63, wid = tid >> 6;
  const int n = tid;
  const size_t bn = (size_t)b * NCELLS;
  const size_t BN = (size_t)BATCH * NCELLS;

  // phase A staging
  __shared__ float s_ww[512], s_prec[512];
  __shared__ float s_rw4[4][512];
  __shared__ float s_bpB[4][4][512];     // 32 KB bwd tree
  __shared__ float s_e[64], s_v[64];
  __shared__ float s_red[8];
  // phase B staging
  __shared__ float s_k[64], s_wk[64];
  __shared__ __align__(16) float s_u[512];
  __shared__ float s_rwB[512];
  __shared__ float s_part[8][64];

  // the link slice for (stripe, b): rows 32*stripe+wid*4+rr, cols jj*64+lane
  float lreg[4][8];
#pragma unroll
  for (int rr = 0; rr < 4; rr++)
#pragma unroll
    for (int jj = 0; jj < 8; jj++) lreg[rr][jj] = 0.f;

  const int i0 = stripe * 32 + wid * 4;

  for (int t = 0; t < TSTEPS; t++) {
    const int cu = t & 1;
    const float* mo = cu ? mem1 : mem0;  float* mn = cu ? mem0 : mem1;
    const float* uo = cu ? us1 : us0;    float* unw = cu ? us0 : us1;
    const float* po = cu ? pr1 : pr0;    float* pnw = cu ? pr0 : pr1;
    const float* ro = cu ? rw1 : rw0;    float* rnw = cu ? rw0 : rw1;
    const float* ifc = iface + ((size_t)b * TSTEPS + t) * IFSZ;

    // ================= phase A =================
    {
      if (wid == 0) s_e[lane] = ifc[325 + lane];
      else if (wid == 1) s_v[lane] = ifc[389 + lane];

      float u_n = uo[bn + n];
      float wcw = wcwb[bn + n];
      float p01 = ppb[0 * BN + bn + n] * ppb[1 * BN + bn + n];
      float p23 = ppb[2 * BN + bn + n] * ppb[3 * BN + bn + n];
      float allocv = (1.f - u_n) * (p01 * p23);
      float ag = ifc[457], wg = ifc[458];
      float wwn = wg * (ag * allocv + (1.f - ag) * wcw);
      s_ww[n] = wwn;
      s_prec[n] = po[bn + n];
#pragma unroll
      for (int r = 0; r < 4; r++) s_rw4[r][n] = ro[bn * RHEADS + (size_t)r * NCELLS + n];
      __syncthreads();

      float wsi[4], rwi[4][4];
#pragma unroll
      for (int rr = 0; rr < 4; rr++) {
        wsi[rr] = s_ww[i0 + rr];
#pragma unroll
        for (int r = 0; r < 4; r++) rwi[rr][r] = s_rw4[r][i0 + rr];
      }
      float facc[4][4];
      float bc[4][8];
#pragma unroll
      for (int a = 0; a < 4; a++)
#pragma unroll
        for (int c = 0; c < 4; c++) facc[a][c] = 0.f;
#pragma unroll
      for (int a = 0; a < 4; a++)
#pragma unroll
        for (int c = 0; c < 8; c++) bc[a][c] = 0.f;

#pragma unroll
      for (int jj = 0; jj < 8; jj++) {
        int j = jj * 64 + lane;
        float swj = s_ww[j], spj = s_prec[j];
        float srw0 = s_rw4[0][j], srw1 = s_rw4[1][j], srw2 = s_rw4[2][j], srw3 = s_rw4[3][j];
#pragma unroll
        for (int rr = 0; rr < 4; rr++) {
          float ln = fmaf(1.f - wsi[rr] - swj, lreg[rr][jj], wsi[rr] * spj);
          if (j == i0 + rr) ln = 0.f;
          lreg[rr][jj] = ln;
          facc[rr][0] = fmaf(ln, srw0, facc[rr][0]);
          facc[rr][1] = fmaf(ln, srw1, facc[rr][1]);
          facc[rr][2] = fmaf(ln, srw2, facc[rr][2]);
          facc[rr][3] = fmaf(ln, srw3, facc[rr][3]);
          bc[0][jj] = fmaf(ln, rwi[rr][0], bc[0][jj]);
          bc[1][jj] = fmaf(ln, rwi[rr][1], bc[1][jj]);
          bc[2][jj] = fmaf(ln, rwi[rr][2], bc[2][jj]);
          bc[3][jj] = fmaf(ln, rwi[rr][3], bc[3][jj]);
        }
      }
#pragma unroll
      for (int rr = 0; rr < 4; rr++) {
#pragma unroll
        for (int r = 0; r < 4; r++) facc[rr][r] = wave_sum(facc[rr][r]);
        if (lane == 0) {
#pragma unroll
          for (int r = 0; r < 4; r++)
            fwdb[((size_t)b * RHEADS + r) * NCELLS + (i0 + rr)] = facc[rr][r];
        }
      }
      // bwd 2-round LDS tree then 4-way sum
      if (wid >= 4) {
#pragma unroll
        for (int r = 0; r < 4; r++)
#pragma unroll
          for (int jj = 0; jj < 8; jj++) s_bpB[wid - 4][r][jj * 64 + lane] = bc[r][jj];
      }
      __syncthreads();
      if (wid < 4) {
#pragma unroll
        for (int r = 0; r < 4; r++)
#pragma unroll
          for (int jj = 0; jj < 8; jj++) s_bpB[wid][r][jj * 64 + lane] += bc[r][jj];
      }
      __syncthreads();
#pragma unroll
      for (int r = 0; r < 4; r++) {
        float a = (s_bpB[0][r][tid] + s_bpB[1][r][tid]) + (s_bpB[2][r][tid] + s_bpB[3][r][tid]);
        bwdp[(((size_t)stripe * BATCH + b) * RHEADS + r) * NCELLS + tid] = a;
      }

      // memory erase+write: this stripe's 32 rows (ping-pong)
      {
        const float* mob = mo + (size_t)b * NCELLS * WORD_SZ + (size_t)stripe * 32 * WORD_SZ;
        float* mnb = mn + (size_t)b * NCELLS * WORD_SZ + (size_t)stripe * 32 * WORD_SZ;
#pragma unroll
        for (int kk = 0; kk < 4; kk++) {
          int flat = tid + kk * 512;
          int nn = stripe * 32 + (flat >> 6), w = flat & 63;
          mnb[flat] = fmaf(mob[flat], 1.f - s_ww[nn] * s_e[w], s_ww[nn] * s_v[w]);
        }
      }
      // usage + precedence (one block per batch)
      if (stripe == 15) {
        float u = u_n + wwn - u_n * wwn;
        float psi = 1.f;
#pragma unroll
        for (int r = 0; r < 4; r++) psi *= (1.f - ifc[453 + r] * s_rw4[r][n]);
        unw[bn + n] = u * psi;
        float sw = block_sum(wwn, s_red, tid);
        pnw[bn + n] = (1.f - sw) * s_prec[n] + wwn;
      }
    }
    grid.sync();

    // ================= phase B (64 blocks) =================
    if (blk < 64) {
      const int r = blk & 3, b2 = blk >> 2;
      const size_t b2n = (size_t)b2 * NCELLS;
      const float* ifcB = iface + ((size_t)b2 * TSTEPS + t) * IFSZ;
      bool have_next = (t + 1 < TSTEPS);
      const float* ifc2 = iface + ((size_t)b2 * TSTEPS + (have_next ? t + 1 : t)) * IFSZ;

      if (wid == 0) {
        float k = ifcB[r * 64 + lane];
        float ss = wave_sum(k * k);
        s_k[lane] = k * rsqrtf(ss + EPSC);
      } else if (wid == 1 && have_next) {
        float k = ifc2[260 + lane];
        float ss = wave_sum(k * k);
        s_wk[lane] = k * rsqrtf(ss + EPSC);
      }
      if (have_next) s_u[tid] = unw[b2n + tid];
      __syncthreads();

      const float4* mrow = (const float4*)(mn + (b2n + n) * WORD_SZ);
      bool do_w = (r == 0) && have_next;
      float msum = 0.f, dot = 0.f, dotw = 0.f;
#pragma unroll
      for (int i = 0; i < 16; i++) {
        float4 m4 = mrow[i];
        msum = fmaf(m4.x, m4.x, fmaf(m4.y, m4.y, fmaf(m4.z, m4.z, fmaf(m4.w, m4.w, msum))));
        dot = fmaf(m4.x, s_k[4 * i], fmaf(m4.y, s_k[4 * i + 1],
              fmaf(m4.z, s_k[4 * i + 2], fmaf(m4.w, s_k[4 * i + 3], dot))));
        if (do_w)
          dotw = fmaf(m4.x, s_wk[4 * i], fmaf(m4.y, s_wk[4 * i + 1],
                 fmaf(m4.z, s_wk[4 * i + 2], fmaf(m4.w, s_wk[4 * i + 3], dotw))));
      }
      float minv = rsqrtf(msum + EPSC);
      float sim = dot * minv * ifcB[256 + r];
      float mx = block_max(sim, s_red, tid);
      float e = expf(sim - mx);
      float ssum = block_sum(e, s_red, tid);
      float rcw = e / ssum;
      float bsum = 0.f;
#pragma unroll
      for (int s = 0; s < NSTRIPE; s++)
        bsum += bwdp[(((size_t)s * BATCH + b2) * RHEADS + r) * NCELLS + n];
      float f = fwdb[((size_t)b2 * RHEADS + r) * NCELLS + n];
      float m0 = ifcB[459 + r * 3], m1 = ifcB[459 + r * 3 + 1], m2 = ifcB[459 + r * 3 + 2];
      float nrw = fmaf(m0, bsum, fmaf(m1, rcw, m2 * f));
      s_rwB[n] = nrw;
      rnw[(b2n * RHEADS) + (size_t)r * NCELLS + n] = nrw;
      __syncthreads();

      // read words
      float acc = 0.f;
      const float* mb = mn + b2n * WORD_SZ;
#pragma unroll 8
      for (int k = 0; k < 64; k++) {
        int nn = wid * 64 + k;
        acc = fmaf(s_rwB[nn], mb[(size_t)nn * WORD_SZ + lane], acc);
      }
      s_part[wid][lane] = acc;
      __syncthreads();
      if (tid < 64) {
        float a = 0.f;
#pragma unroll
        for (int w = 0; w < 8; w++) a += s_part[w][tid];
        out[(((size_t)b2 * TSTEPS + t) * RHEADS + r) * WORD_SZ + tid] = a;
      }

      // next-step ww ingredients
      if (have_next) {
        float un = s_u[n];
        int base = r * 128;
        float p0 = 1.f, p1 = 1.f, p2 = 1.f, p3 = 1.f;
#pragma unroll 8
        for (int j = 0; j < 128; j += 4) {
          float4 u4 = *(const float4*)&s_u[base + j];
          int ja = base + j;
          p0 *= (u4.x < un || (u4.x == un && (ja + 0) < n)) ? u4.x : 1.f;
          p1 *= (u4.y < un || (u4.y == un && (ja + 1) < n)) ? u4.y : 1.f;
          p2 *= (u4.z < un || (u4.z == un && (ja + 2) < n)) ? u4.z : 1.f;
          p3 *= (u4.w < un || (u4.w == un && (ja + 3) < n)) ? u4.w : 1.f;
        }
        ppb[((size_t)r * BATCH + b2) * NCELLS + n] = (p0 * p1) * (p2 * p3);
        if (r == 0) {
          float simw = dotw * minv * ifc2[324];
          float mxw = block_max(simw, s_red, tid);
          float ew = expf(simw - mxw);
          float ssw = block_sum(ew, s_red, tid);
          wcwb[b2n + n] = ew / ssw;
        }
      }
    }
    grid.sync();
  }
}

// ---------- host ----------
extern "C" void kernel_launch(void* const* d_in, const int* in_sizes, int n_in,
                              void* d_out, int out_size, void* d_ws, size_t ws_size,
                              hipStream_t stream) {
  const float* ctrl = (const float*)d_in[0];
  const float* Wif = (const float*)d_in[1];
  const float* bif = (const float*)d_in[2];
  float* out = (float*)d_out;

  float* p = (float*)d_ws;
  float* mem0 = p;   p += (size_t)BATCH * NCELLS * WORD_SZ;
  float* mem1 = p;   p += (size_t)BATCH * NCELLS * WORD_SZ;
  float* iface = p;  p += (size_t)BATCH * TSTEPS * IFSZ;
  float* rw0 = p;    p += (size_t)BATCH * RHEADS * NCELLS;
  float* rw1 = p;    p += (size_t)BATCH * RHEADS * NCELLS;
  float* us0 = p;    p += (size_t)BATCH * NCELLS;
  float* us1 = p;    p += (size_t)BATCH * NCELLS;
  float* pr0 = p;    p += (size_t)BATCH * NCELLS;
  float* pr1 = p;    p += (size_t)BATCH * NCELLS;
  float* fwdb = p;   p += (size_t)BATCH * RHEADS * NCELLS;
  float* bwdp = p;   p += (size_t)NSTRIPE * BATCH * RHEADS * NCELLS;
  float* wcwb = p;   p += (size_t)BATCH * NCELLS;
  float* ppb = p;    p += (size_t)4 * BATCH * NCELLS;

  hipLaunchKernelGGL(init_kernel, dim3(256), dim3(256), 0, stream,
                     mem0, rw0, us0, pr0, wcwb, ppb);
  hipLaunchKernelGGL(iface_kernel, dim3(BATCH * TSTEPS), dim3(512), 0, stream,
                     ctrl, Wif, bif, iface);

  void* args[] = {(void*)&iface, (void*)&mem0, (void*)&mem1,
                  (void*)&rw0, (void*)&rw1, (void*)&us0, (void*)&us1,
                  (void*)&pr0, (void*)&pr1, (void*)&wcwb, (void*)&ppb,
                  (void*)&fwdb, (void*)&bwdp, (void*)&out};
  hipLaunchCooperativeKernel((void*)dnc_loop, dim3(256), dim3(512), args, 0, stream);
}

// Round 4
// 1165.938 us; speedup vs baseline: 2.3414x; 2.3414x over previous
//
#include <hip/hip_runtime.h>

#define NC 512
#define WSZ 64
#define RH 4
#define BA 16
#define TS 32
#define IFSZ 471
#define EPSC 1e-8f

// ---------- helpers ----------
__device__ __forceinline__ float wave_sum(float v) {
#pragma unroll
  for (int m = 32; m >= 1; m >>= 1) v += __shfl_xor(v, m, 64);
  return v;
}
__device__ __forceinline__ float wave_max(float v) {
#pragma unroll
  for (int m = 32; m >= 1; m >>= 1) v = fmaxf(v, __shfl_xor(v, m, 64));
  return v;
}
__device__ __forceinline__ float block_sum(float v, float* s_red, int tid) {
  float w = wave_sum(v);
  if ((tid & 63) == 0) s_red[tid >> 6] = w;
  __syncthreads();
  float tot = 0.f;
#pragma unroll
  for (int i = 0; i < 8; i++) tot += s_red[i];
  __syncthreads();
  return tot;
}
__device__ __forceinline__ float softplus_f(float x) {
  return fmaxf(x, 0.f) + log1pf(expf(-fabsf(x)));
}
__device__ __forceinline__ float sigmoid_f(float x) {
  return 1.f / (1.f + expf(-x));
}

// ---------- init ----------
__global__ void init_kernel(float* link, float* mem, float* us, float* pr,
                            float* ppb, float* rwi, float* wcwi) {
  size_t i = (size_t)blockIdx.x * blockDim.x + threadIdx.x;
  size_t stride = (size_t)gridDim.x * blockDim.x;
  for (size_t x = i; x < (size_t)BA * NC * NC; x += stride) link[x] = 0.f;
  for (size_t x = i; x < (size_t)BA * NC * WSZ; x += stride) mem[x] = 0.f;
  for (size_t x = i; x < (size_t)BA * RH * NC; x += stride) rwi[x] = 1.f / NC;
  for (size_t x = i; x < (size_t)BA * NC; x += stride) {
    us[x] = 0.f; pr[x] = 0.f; wcwi[x] = 1.f / NC;
  }
  for (size_t x = i; x < (size_t)16 * BA * NC; x += stride) {
    int s = (int)(x / (BA * NC));
    int n = (int)(x % NC);
    // partial product over j in [32s,32s+32) with usage==0: factor 0 iff j<n exists
    ppb[x] = (n > 32 * s) ? 0.f : 1.f;
  }
}

// ---------- interface GEMM + activations (once) ----------
__global__ __launch_bounds__(512) void iface_kernel(
    const float* __restrict__ ctrl, const float* __restrict__ W,
    const float* __restrict__ bif, float* __restrict__ iface) {
  int bt = blockIdx.x;
  int tid = threadIdx.x;
  __shared__ float s_ctrl[512];
  __shared__ float s_v[IFSZ];
  s_ctrl[tid] = ctrl[(size_t)bt * 512 + tid];
  __syncthreads();
  if (tid < IFSZ) {
    float acc = bif[tid];
#pragma unroll 8
    for (int k = 0; k < 512; k++) acc = fmaf(s_ctrl[k], W[(size_t)k * IFSZ + tid], acc);
    s_v[tid] = acc;
  }
  __syncthreads();
  if (tid < IFSZ) {
    float v = s_v[tid];
    float o;
    if (tid < 256) o = v;
    else if (tid < 260) o = softplus_f(v);
    else if (tid < 324) o = v;
    else if (tid < 325) o = softplus_f(v);
    else if (tid < 389) o = sigmoid_f(v);
    else if (tid < 453) o = v;
    else if (tid < 459) o = sigmoid_f(v);
    else {
      int g = (tid - 459) / 3;
      int base = 459 + g * 3;
      float a = s_v[base], b = s_v[base + 1], c = s_v[base + 2];
      float mx = fmaxf(a, fmaxf(b, c));
      float ea = expf(a - mx), eb = expf(b - mx), ec = expf(c - mx);
      o = expf(v - mx) / (ea + eb + ec);
    }
    iface[(size_t)bt * IFSZ + tid] = o;
  }
}

// ---------- fused per-step kernel: [read-phase of t-1 recomputed locally] + [write/link of t] ----------
__global__ __launch_bounds__(512) void fused_step(
    const float* __restrict__ iface,
    const float* __restrict__ mem_cur, float* __restrict__ mem_nxt,
    const float* __restrict__ us_old, float* __restrict__ us_new,
    const float* __restrict__ pr_old, float* __restrict__ pr_new,
    const float* __restrict__ ppb_old, float* __restrict__ ppb_new,
    const float* __restrict__ fwd_old, float* __restrict__ fwd_new,
    const float* __restrict__ bwd_old, float* __restrict__ bwd_new,
    const float* __restrict__ rw_init, const float* __restrict__ wcw_init,
    float* __restrict__ link, float* __restrict__ out, int t) {
  const int stripe = blockIdx.x, b = blockIdx.y;
  const int tid = threadIdx.x, lane = tid & 63, wid = tid >> 6;
  const int n = tid;
  const size_t bn = (size_t)b * NC;
  const float* ifcA = iface + ((size_t)b * TS + t) * IFSZ;

  __shared__ float s_rw4[4][NC];          // rw carry entering step t
  __shared__ float s_ww[NC], s_prec[NC], s_unew[NC];
  __shared__ float s_bpB[4][4][NC];       // 32 KB bwd tree
  __shared__ float s_keys[5][64];         // 4 read keys (t-1) + write key (t)
  __shared__ float s_e[64], s_v[64];
  __shared__ float s_red[8];
  __shared__ float s_red5[8][5];
  __shared__ float s_part[8][4][64];

  float wcw;
  // ================= phase B: read step for t-1 (recomputed in every block) =================
  if (t > 0) {
    const float* ifcB = ifcA - IFSZ;
    if (wid < 4) {
      float k = ifcB[wid * 64 + lane];
      float ss = wave_sum(k * k);
      s_keys[wid][lane] = k * rsqrtf(ss + EPSC);
    } else if (wid == 4) {
      float k = ifcA[260 + lane];
      float ss = wave_sum(k * k);
      s_keys[4][lane] = k * rsqrtf(ss + EPSC);
    }
    __syncthreads();

    const float4* mrow = (const float4*)(mem_cur + (bn + n) * WSZ);
    float msum = 0.f, dt0 = 0.f, dt1 = 0.f, dt2 = 0.f, dt3 = 0.f, dtw = 0.f;
#pragma unroll
    for (int i = 0; i < 16; i++) {
      float4 m4 = mrow[i];
      msum = fmaf(m4.x, m4.x, fmaf(m4.y, m4.y, fmaf(m4.z, m4.z, fmaf(m4.w, m4.w, msum))));
      dt0 = fmaf(m4.x, s_keys[0][4 * i], fmaf(m4.y, s_keys[0][4 * i + 1],
            fmaf(m4.z, s_keys[0][4 * i + 2], fmaf(m4.w, s_keys[0][4 * i + 3], dt0))));
      dt1 = fmaf(m4.x, s_keys[1][4 * i], fmaf(m4.y, s_keys[1][4 * i + 1],
            fmaf(m4.z, s_keys[1][4 * i + 2], fmaf(m4.w, s_keys[1][4 * i + 3], dt1))));
      dt2 = fmaf(m4.x, s_keys[2][4 * i], fmaf(m4.y, s_keys[2][4 * i + 1],
            fmaf(m4.z, s_keys[2][4 * i + 2], fmaf(m4.w, s_keys[2][4 * i + 3], dt2))));
      dt3 = fmaf(m4.x, s_keys[3][4 * i], fmaf(m4.y, s_keys[3][4 * i + 1],
            fmaf(m4.z, s_keys[3][4 * i + 2], fmaf(m4.w, s_keys[3][4 * i + 3], dt3))));
      dtw = fmaf(m4.x, s_keys[4][4 * i], fmaf(m4.y, s_keys[4][4 * i + 1],
            fmaf(m4.z, s_keys[4][4 * i + 2], fmaf(m4.w, s_keys[4][4 * i + 3], dtw))));
    }
    float minv = rsqrtf(msum + EPSC);
    float sim[5];
    sim[0] = dt0 * minv * ifcB[256];
    sim[1] = dt1 * minv * ifcB[257];
    sim[2] = dt2 * minv * ifcB[258];
    sim[3] = dt3 * minv * ifcB[259];
    sim[4] = dtw * minv * ifcA[324];
    // 5-value block max (one sync pair)
#pragma unroll
    for (int i = 0; i < 5; i++) {
      float wm = wave_max(sim[i]);
      if (lane == 0) s_red5[wid][i] = wm;
    }
    __syncthreads();
    float ex[5];
#pragma unroll
    for (int i = 0; i < 5; i++) {
      float mx = s_red5[0][i];
#pragma unroll
      for (int w = 1; w < 8; w++) mx = fmaxf(mx, s_red5[w][i]);
      ex[i] = expf(sim[i] - mx);
    }
    __syncthreads();
#pragma unroll
    for (int i = 0; i < 5; i++) {
      float ws_ = wave_sum(ex[i]);
      if (lane == 0) s_red5[wid][i] = ws_;
    }
    __syncthreads();
    float den[5];
#pragma unroll
    for (int i = 0; i < 5; i++) {
      float s = 0.f;
#pragma unroll
      for (int w = 0; w < 8; w++) s += s_red5[w][i];
      den[i] = s;
    }
    wcw = ex[4] / den[4];
    // rw carry = mode mix of {bwd, content, fwd}
#pragma unroll
    for (int r = 0; r < 4; r++) {
      float bs = 0.f;
#pragma unroll
      for (int s = 0; s < 16; s++)
        bs += bwd_old[(((size_t)s * BA + b) * RH + r) * NC + n];
      float f = fwd_old[((size_t)b * RH + r) * NC + n];
      float rcw = ex[r] / den[r];
      float m0 = ifcB[459 + r * 3], m1 = ifcB[459 + r * 3 + 1], m2 = ifcB[459 + r * 3 + 2];
      s_rw4[r][n] = fmaf(m0, bs, fmaf(m1, rcw, m2 * f));
    }
    __syncthreads();
    // read words -> out[t-1] (stripe 0 blocks only; barrier is block-uniform)
    if (stripe == 0) {
      float acc[4] = {0.f, 0.f, 0.f, 0.f};
      const float* mb = mem_cur + bn * WSZ;
#pragma unroll 8
      for (int k = 0; k < 64; k++) {
        int nn = wid * 64 + k;
        float m = mb[(size_t)nn * WSZ + lane];
#pragma unroll
        for (int r = 0; r < 4; r++) acc[r] = fmaf(s_rw4[r][nn], m, acc[r]);
      }
#pragma unroll
      for (int r = 0; r < 4; r++) s_part[wid][r][lane] = acc[r];
      __syncthreads();
      if (tid < 256) {
        int r = tid >> 6, w = tid & 63;
        float a = 0.f;
#pragma unroll
        for (int wv = 0; wv < 8; wv++) a += s_part[wv][r][w];
        out[(((size_t)b * TS + (t - 1)) * RH + r) * WSZ + w] = a;
      }
    }
  } else {
    // t == 0: carry state from init
#pragma unroll
    for (int r = 0; r < 4; r++) s_rw4[r][n] = rw_init[((size_t)b * RH + r) * NC + n];
    wcw = wcw_init[bn + n];
    __syncthreads();
  }

  // ================= phase A: write weights, link, memory, usage, prec =================
  if (wid == 0) s_e[lane] = ifcA[325 + lane];
  else if (wid == 1) s_v[lane] = ifcA[389 + lane];

  float u_n = us_old[bn + n];
  float pp = 1.f;
#pragma unroll
  for (int s = 0; s < 16; s++) pp *= ppb_old[((size_t)s * BA + b) * NC + n];
  float allocv = (1.f - u_n) * pp;
  float ag = ifcA[457], wg = ifcA[458];
  float wwn = wg * (ag * allocv + (1.f - ag) * wcw);
  s_ww[n] = wwn;
  s_prec[n] = pr_old[bn + n];
  __syncthreads();

  const int i0 = stripe * 32 + wid * 4;
  float wsi[4], rwi[4][4];
#pragma unroll
  for (int rr = 0; rr < 4; rr++) {
    wsi[rr] = s_ww[i0 + rr];
#pragma unroll
    for (int r = 0; r < 4; r++) rwi[rr][r] = s_rw4[r][i0 + rr];
  }
  float facc[4][4];
  float bc[4][8];
#pragma unroll
  for (int a = 0; a < 4; a++)
#pragma unroll
    for (int c = 0; c < 4; c++) facc[a][c] = 0.f;
#pragma unroll
  for (int a = 0; a < 4; a++)
#pragma unroll
    for (int c = 0; c < 8; c++) bc[a][c] = 0.f;

  float* lbase = link + (size_t)b * NC * NC;
#pragma unroll
  for (int jj = 0; jj < 8; jj++) {
    int j = jj * 64 + lane;
    float swj = s_ww[j], spj = s_prec[j];
    float srw0 = s_rw4[0][j], srw1 = s_rw4[1][j], srw2 = s_rw4[2][j], srw3 = s_rw4[3][j];
#pragma unroll
    for (int rr = 0; rr < 4; rr++) {
      float* lp = lbase + (size_t)(i0 + rr) * NC + j;
      float l = *lp;
      float ln = fmaf(1.f - wsi[rr] - swj, l, wsi[rr] * spj);
      if (j == i0 + rr) ln = 0.f;
      *lp = ln;
      facc[rr][0] = fmaf(ln, srw0, facc[rr][0]);
      facc[rr][1] = fmaf(ln, srw1, facc[rr][1]);
      facc[rr][2] = fmaf(ln, srw2, facc[rr][2]);
      facc[rr][3] = fmaf(ln, srw3, facc[rr][3]);
      bc[0][jj] = fmaf(ln, rwi[rr][0], bc[0][jj]);
      bc[1][jj] = fmaf(ln, rwi[rr][1], bc[1][jj]);
      bc[2][jj] = fmaf(ln, rwi[rr][2], bc[2][jj]);
      bc[3][jj] = fmaf(ln, rwi[rr][3], bc[3][jj]);
    }
  }
#pragma unroll
  for (int rr = 0; rr < 4; rr++) {
#pragma unroll
    for (int r = 0; r < 4; r++) facc[rr][r] = wave_sum(facc[rr][r]);
    if (lane == 0) {
#pragma unroll
      for (int r = 0; r < 4; r++)
        fwd_new[((size_t)b * RH + r) * NC + (i0 + rr)] = facc[rr][r];
    }
  }
  // bwd 2-round LDS tree then 4-way sum
  if (wid >= 4) {
#pragma unroll
    for (int r = 0; r < 4; r++)
#pragma unroll
      for (int jj = 0; jj < 8; jj++) s_bpB[wid - 4][r][jj * 64 + lane] = bc[r][jj];
  }
  __syncthreads();
  if (wid < 4) {
#pragma unroll
    for (int r = 0; r < 4; r++)
#pragma unroll
      for (int jj = 0; jj < 8; jj++) s_bpB[wid][r][jj * 64 + lane] += bc[r][jj];
  }
  __syncthreads();
#pragma unroll
  for (int r = 0; r < 4; r++) {
    float a = (s_bpB[0][r][tid] + s_bpB[1][r][tid]) + (s_bpB[2][r][tid] + s_bpB[3][r][tid]);
    bwd_new[(((size_t)stripe * BA + b) * RH + r) * NC + tid] = a;
  }

  // memory erase+write for this stripe's 32 rows (ping-pong)
  {
    const float* mob = mem_cur + bn * WSZ + (size_t)stripe * 32 * WSZ;
    float* mnb = mem_nxt + bn * WSZ + (size_t)stripe * 32 * WSZ;
#pragma unroll
    for (int kk = 0; kk < 4; kk++) {
      int flat = tid + kk * 512;
      int nn = stripe * 32 + (flat >> 6), w = flat & 63;
      mnb[flat] = fmaf(mob[flat], 1.f - s_ww[nn] * s_e[w], s_ww[nn] * s_v[w]);
    }
  }

  // usage update (computed by every block for the alloc partials)
  float u = u_n + wwn - u_n * wwn;
  float psi = 1.f;
#pragma unroll
  for (int r = 0; r < 4; r++) psi *= (1.f - ifcA[453 + r] * s_rw4[r][n]);
  float unew = u * psi;
  s_unew[n] = unew;
  __syncthreads();

  // allocation partial product over this stripe's 32-j slice (for step t+1)
  {
    float p = 1.f;
    int base = stripe * 32;
#pragma unroll
    for (int jj = 0; jj < 32; jj++) {
      int j = base + jj;
      float uj = s_unew[j];
      bool take = (uj < unew) || (uj == unew && j < n);
      p *= take ? uj : 1.f;
    }
    ppb_new[((size_t)stripe * BA + b) * NC + n] = p;
  }
  if (stripe == 15) {
    us_new[bn + n] = unew;
    float sw = block_sum(wwn, s_red, tid);
    pr_new[bn + n] = (1.f - sw) * s_prec[n] + wwn;
  }
}

// ---------- final read step (t = 31) ----------
__global__ __launch_bounds__(512) void final_read(
    const float* __restrict__ iface, const float* __restrict__ mem_cur,
    const float* __restrict__ fwd_old, const float* __restrict__ bwd_old,
    float* __restrict__ out) {
  const int r = blockIdx.x, b = blockIdx.y;
  const int tid = threadIdx.x, lane = tid & 63, wid = tid >> 6;
  const int n = tid;
  const int t = TS - 1;
  const size_t bn = (size_t)b * NC;
  const float* ifc = iface + ((size_t)b * TS + t) * IFSZ;
  __shared__ float s_k[64];
  __shared__ float s_rw[NC];
  __shared__ float s_part[8][64];
  __shared__ float s_red[8];

  if (wid == 0) {
    float k = ifc[r * 64 + lane];
    float ss = wave_sum(k * k);
    s_k[lane] = k * rsqrtf(ss + EPSC);
  }
  __syncthreads();

  const float4* mrow = (const float4*)(mem_cur + (bn + n) * WSZ);
  float msum = 0.f, dot = 0.f;
#pragma unroll
  for (int i = 0; i < 16; i++) {
    float4 m4 = mrow[i];
    msum = fmaf(m4.x, m4.x, fmaf(m4.y, m4.y, fmaf(m4.z, m4.z, fmaf(m4.w, m4.w, msum))));
    dot = fmaf(m4.x, s_k[4 * i], fmaf(m4.y, s_k[4 * i + 1],
          fmaf(m4.z, s_k[4 * i + 2], fmaf(m4.w, s_k[4 * i + 3], dot))));
  }
  float sim = dot * rsqrtf(msum + EPSC) * ifc[256 + r];
  float wm = wave_max(sim);
  if (lane == 0) s_red[wid] = wm;
  __syncthreads();
  float mx = s_red[0];
#pragma unroll
  for (int i = 1; i < 8; i++) mx = fmaxf(mx, s_red[i]);
  __syncthreads();
  float e = expf(sim - mx);
  float ssum = block_sum(e, s_red, tid);
  float rcw = e / ssum;
  float bs = 0.f;
#pragma unroll
  for (int s = 0; s < 16; s++)
    bs += bwd_old[(((size_t)s * BA + b) * RH + r) * NC + n];
  float f = fwd_old[((size_t)b * RH + r) * NC + n];
  float m0 = ifc[459 + r * 3], m1 = ifc[459 + r * 3 + 1], m2 = ifc[459 + r * 3 + 2];
  s_rw[n] = fmaf(m0, bs, fmaf(m1, rcw, m2 * f));
  __syncthreads();

  float acc = 0.f;
  const float* mb = mem_cur + bn * WSZ;
#pragma unroll 8
  for (int k = 0; k < 64; k++) {
    int nn = wid * 64 + k;
    acc = fmaf(s_rw[nn], mb[(size_t)nn * WSZ + lane], acc);
  }
  s_part[wid][lane] = acc;
  __syncthreads();
  if (tid < 64) {
    float a = 0.f;
#pragma unroll
    for (int w = 0; w < 8; w++) a += s_part[w][tid];
    out[(((size_t)b * TS + t) * RH + r) * WSZ + tid] = a;
  }
}

// ---------- host ----------
extern "C" void kernel_launch(void* const* d_in, const int* in_sizes, int n_in,
                              void* d_out, int out_size, void* d_ws, size_t ws_size,
                              hipStream_t stream) {
  const float* ctrl = (const float*)d_in[0];
  const float* Wif = (const float*)d_in[1];
  const float* bif = (const float*)d_in[2];
  float* out = (float*)d_out;

  float* p = (float*)d_ws;
  float* link = p;    p += (size_t)BA * NC * NC;
  float* mem0 = p;    p += (size_t)BA * NC * WSZ;
  float* mem1 = p;    p += (size_t)BA * NC * WSZ;
  float* iface = p;   p += (size_t)BA * TS * IFSZ;
  float* us0 = p;     p += (size_t)BA * NC;
  float* us1 = p;     p += (size_t)BA * NC;
  float* pr0 = p;     p += (size_t)BA * NC;
  float* pr1 = p;     p += (size_t)BA * NC;
  float* ppb0 = p;    p += (size_t)16 * BA * NC;
  float* ppb1 = p;    p += (size_t)16 * BA * NC;
  float* fwd0 = p;    p += (size_t)BA * RH * NC;
  float* fwd1 = p;    p += (size_t)BA * RH * NC;
  float* bwd0 = p;    p += (size_t)16 * BA * RH * NC;
  float* bwd1 = p;    p += (size_t)16 * BA * RH * NC;
  float* rwi = p;     p += (size_t)BA * RH * NC;
  float* wcwi = p;    p += (size_t)BA * NC;

  float* mem[2] = {mem0, mem1};
  float* us[2] = {us0, us1};
  float* pr[2] = {pr0, pr1};
  float* ppb[2] = {ppb0, ppb1};
  float* fwd[2] = {fwd0, fwd1};
  float* bwd[2] = {bwd0, bwd1};

  hipLaunchKernelGGL(init_kernel, dim3(2048), dim3(256), 0, stream,
                     link, mem0, us0, pr0, ppb0, rwi, wcwi);
  hipLaunchKernelGGL(iface_kernel, dim3(BA * TS), dim3(512), 0, stream,
                     ctrl, Wif, bif, iface);
  for (int t = 0; t < TS; t++) {
    int cp = t & 1, cq = cp ^ 1;
    hipLaunchKernelGGL(fused_step, dim3(16, BA), dim3(512), 0, stream,
                       iface, mem[cp], mem[cq], us[cp], us[cq], pr[cp], pr[cq],
                       ppb[cp], ppb[cq], fwd[cp], fwd[cq], bwd[cp], bwd[cq],
                       rwi, wcwi, link, out, t);
  }
  hipLaunchKernelGGL(final_read, dim3(RH, BA), dim3(512), 0, stream,
                     iface, mem[0], fwd[0], bwd[0], out);
}